// Round 12
// baseline (1657.594 us; speedup 1.0000x reference)
//
#include <hip/hip_runtime.h>

#define NN 100000
#define EE 6400000
#define PP 12
#define FF 32

// bucket = 128 consecutive node ids; recs2 is globally bucket-contiguous
#define VV    128           // nodes per bucket
#define BB    782           // ceil(NN/VV)
#define CAPB  8832          // per-bucket region capacity: mean 8192 + 7 sigma
#define K1B   800           // chunks
#define CHK   8000          // edges per chunk (K1B*CHK == EE)
#define NBIN  784           // hist bins padded (782 used)
#define XST   16            // xds row stride (floats): 64B -> one cache line per node
#define NSEG  4             // sortagg segments per bucket (contiguous quarters)
#define CAP2  2432          // per-segment LDS capacity >= ceil(CAPB/4)=2208
#define NR2   5             // records per thread (ceil(CAP2/512))
#define FPS   4294967296.0f // fixed-point scale 2^32
#define FPSI  (1.0f / 4294967296.0f)

// ---------------- K1a: per-chunk bucket histogram -> T16 counts ----------------
// T16[b*K1B + blk] = count of bucket-b records in chunk blk
__global__ __launch_bounds__(512) void hist_k(const int* __restrict__ dst,
                                              unsigned short* __restrict__ T16) {
    __shared__ int hist[NBIN];
    int tid = threadIdx.x;
    int blk = blockIdx.x;
    int beg = blk * CHK;

    for (int b = tid; b < NBIN; b += 512) hist[b] = 0;
    __syncthreads();

    for (int e = tid; e < CHK; e += 512)
        atomicAdd(&hist[dst[beg + e] >> 7], 1);
    __syncthreads();

    for (int b = tid; b < BB; b += 512)
        T16[(size_t)b * K1B + blk] = (unsigned short)hist[b];
}

// ---------------- K1b: per-bucket row scan -> P32 (excl prefix), tot; + precompute --
// block b<BB: P32[b][k] = sum of T16[b][0..k); tot[b] = row total
// block BB: GRU table precompute (tabs: [0..11] probs, [16..143] az/cz/ah/ch)
__global__ __launch_bounds__(512) void scan_k(const unsigned short* __restrict__ T16,
                                              unsigned int* __restrict__ P32,
                                              unsigned int* __restrict__ tot,
                                              const float* __restrict__ att,
                                              const float* __restrict__ wc_z, const float* __restrict__ bc_z,
                                              const float* __restrict__ wc_h, const float* __restrict__ bc_h,
                                              const float* __restrict__ wl_z, const float* __restrict__ bl_z,
                                              const float* __restrict__ wl_h, const float* __restrict__ bl_h,
                                              float* __restrict__ tabs) {
    int b = blockIdx.x;
    int tid = threadIdx.x;

    if (b == BB) {                      // fused precompute (one block)
        int j = tid;
        if (j < FF) {
            float az = 0.f, cz = 0.f, ah = 0.f, ch = 0.f;
            for (int f = 0; f < FF; ++f) {
                float wz = wl_z[f * FF + j];
                float wh = wl_h[f * FF + j];
                az += wc_z[f] * wz;
                cz += bc_z[f] * wz;
                ah += wc_h[f] * wh;
                ch += bc_h[f] * wh;
            }
            tabs[16 + j]          = az;
            tabs[16 + FF + j]     = cz + bl_z[j];
            tabs[16 + 2 * FF + j] = ah;
            tabs[16 + 3 * FF + j] = ch + bl_h[j];
        } else if (j == FF) {
            float a[PP];
            float m = -1e30f;
            for (int p = 0; p < PP; ++p) { a[p] = att[p]; m = fmaxf(m, a[p]); }
            float s = 0.f;
            for (int p = 0; p < PP; ++p) { a[p] = __expf(a[p] - m); s += a[p]; }
            for (int p = 0; p < PP; ++p) tabs[p] = a[p] / s;
        }
        return;
    }

    __shared__ int s[K1B];
    int i2 = tid + 512;
    s[tid] = T16[(size_t)b * K1B + tid];
    if (i2 < K1B) s[i2] = T16[(size_t)b * K1B + i2];
    __syncthreads();

    int own0 = s[tid];
    int own1 = (i2 < K1B) ? s[i2] : 0;
    for (int off = 1; off < K1B; off <<= 1) {   // off: 1..512
        int a0 = (tid >= off) ? s[tid - off] : 0;
        int a1 = (i2 < K1B) ? s[i2 - off] : 0;  // i2 >= 512 >= off always
        __syncthreads();
        s[tid] += a0;
        if (i2 < K1B) s[i2] += a1;
        __syncthreads();
    }
    P32[(size_t)b * K1B + tid] = (unsigned)(s[tid] - own0);
    if (i2 < K1B) P32[(size_t)b * K1B + i2] = (unsigned)(s[i2] - own1);
    if (tid == 0) tot[b] = (unsigned)s[K1B - 1];
}

// ---------------- K1c: chunk-sort in LDS, scatter runs to global bucket regions -----
// record: (local<<17)|src, bits(w); target recs2[b*CAPB + P32[b][blk] + rank]
__global__ __launch_bounds__(512) void sortwrite_k(const int* __restrict__ src,
                                                   const int* __restrict__ dst,
                                                   const float* __restrict__ ew,
                                                   const unsigned short* __restrict__ T16,
                                                   const unsigned int* __restrict__ P32,
                                                   uint2* __restrict__ recs2) {
    __shared__ unsigned int perm[CHK];      // 32000 B: (bucket<<20)|(local<<13)|e
    __shared__ int cnt_s[NBIN];             // counts -> inclusive scan
    __shared__ int offs[NBIN];              // claim counters (start at lstart)
    __shared__ unsigned short lstart[NBIN]; // chunk-local run starts
    __shared__ unsigned int gbase[NBIN];    // global run bases
    int tid = threadIdx.x;
    int blk = blockIdx.x;
    int beg = blk * CHK;

    for (int b = tid; b < NBIN; b += 512) {
        int c = (b < BB) ? (int)T16[(size_t)b * K1B + blk] : 0;
        cnt_s[b] = c;
        gbase[b] = (b < BB) ? (unsigned)(b * CAPB) + P32[(size_t)b * K1B + blk] : 0u;
    }
    __syncthreads();

    // inclusive Hillis-Steele scan over cnt_s[NBIN], 2 slots/thread
    int i2   = 512 + tid;
    int own0 = cnt_s[tid];
    int own1 = (i2 < NBIN) ? cnt_s[i2] : 0;
    for (int off = 1; off < NBIN; off <<= 1) {
        int a0 = (tid >= off) ? cnt_s[tid - off] : 0;
        int a1 = (i2 < NBIN) ? cnt_s[i2 - off] : 0;   // i2 >= 512 >= off always
        __syncthreads();
        cnt_s[tid] += a0;
        if (i2 < NBIN) cnt_s[i2] += a1;
        __syncthreads();
    }
    offs[tid]   = cnt_s[tid] - own0;
    lstart[tid] = (unsigned short)(cnt_s[tid] - own0);
    if (i2 < NBIN) {
        offs[i2]   = cnt_s[i2] - own1;
        lstart[i2] = (unsigned short)(cnt_s[i2] - own1);
    }
    __syncthreads();

    // placement: LDS claim atomic + 4B perm store (dst re-read is L1/L2-hot)
    for (int e = tid; e < CHK; e += 512) {
        int d = dst[beg + e];
        int b = d >> 7;
        int p = atomicAdd(&offs[b], 1);
        perm[p] = ((unsigned)b << 20) | ((unsigned)(d & (VV - 1)) << 13) | (unsigned)e;
    }
    __syncthreads();

    // write-out: runs land contiguous in their bucket region (82B avg granules)
    for (int k = tid; k < CHK; k += 512) {
        unsigned pe = perm[k];
        int b = (int)(pe >> 20);
        int e = (int)(pe & 0x1FFFu);
        unsigned g = gbase[b] + (unsigned)(k - (int)lstart[b]);
        if (g < (unsigned)((b + 1) * CAPB)) {
            uint2 r;
            r.x = (((pe >> 13) & 0x7Fu) << 17) | (unsigned)src[beg + e];
            r.y = __float_as_uint(ew[beg + e]);
            recs2[g] = r;
        }
    }
}

// ---------------- K2: per-bucket degree (coalesced stream + ds_add_u64) + xds -------
__global__ __launch_bounds__(512) void degxds_k(const uint2* __restrict__ recs2,
                                                const unsigned int* __restrict__ tot,
                                                const float* __restrict__ x,
                                                float* __restrict__ xds) {
    __shared__ unsigned long long wsum[VV];
    int b = blockIdx.x;
    int tid = threadIdx.x;
    if (tid < VV) wsum[tid] = 0ull;
    __syncthreads();

    int n = min((int)tot[b], CAPB);
    const uint2* r = recs2 + (size_t)b * CAPB;
    for (int k = tid; k < n; k += 512) {
        uint2 v = r[k];
        atomicAdd(&wsum[v.x >> 17],
                  (unsigned long long)(long long)(__uint_as_float(v.y) * FPS));
    }
    __syncthreads();

    int node = b * VV + tid;
    if (tid < VV && node < NN) {
        float wf = (float)wsum[tid] * FPSI;
        float dv = rsqrtf(wf + 1.0f);
        const float4* xr = (const float4*)(x + (size_t)node * PP);
        float4* xo = (float4*)(xds + ((size_t)node << 4));
        #pragma unroll
        for (int q = 0; q < 3; ++q) {
            float4 v = xr[q];
            v.x *= dv; v.y *= dv; v.z *= dv; v.w *= dv;
            xo[q] = v;
        }
        xds[((size_t)node << 4) + 12] = dv;
    }
}

// ---------------- K3: sortagg on contiguous quarters + last-finisher epilogue -------
__global__ __launch_bounds__(512) void sortagg_k(const uint2* __restrict__ recs2,
                                                 const unsigned int* __restrict__ tot,
                                                 const float* __restrict__ xds,
                                                 float* __restrict__ pagg,
                                                 int* __restrict__ cnt,
                                                 const float* __restrict__ tabs,
                                                 const float* __restrict__ w_out,
                                                 const float* __restrict__ b_out,
                                                 float* __restrict__ out) {
    __shared__ uint2 srec[CAP2];                    // 19456 B
    __shared__ int   h[VV], starts_s[VV], offs[VV]; // 1536 B (h keeps inclusive ends)
    __shared__ int   is_last;
    int b   = blockIdx.x >> 2;
    int seg = blockIdx.x & 3;
    int tid = threadIdx.x;

    int n  = min((int)tot[b], CAPB);
    int lo = (n * seg) >> 2;
    int hi = (n * (seg + 1)) >> 2;
    int cs = hi - lo;                               // <= ceil(CAPB/4) = 2208 <= CAP2
    const uint2* base = recs2 + (size_t)b * CAPB + lo;

    if (tid < VV) h[tid] = 0;
    __syncthreads();

    // dense coalesced load into REGISTERS + node histogram
    uint2 regs[NR2];
    #pragma unroll
    for (int w = 0; w < NR2; ++w) {
        int k = tid + w * 512;
        if (k < cs) {
            uint2 v = base[k];
            regs[w] = v;
            atomicAdd(&h[v.x >> 17], 1);
        }
    }
    __syncthreads();

    // Hillis-Steele inclusive scan over h[VV]; h stays = inclusive end
    int own = (tid < VV) ? h[tid] : 0;
    #pragma unroll
    for (int off = 1; off < VV; off <<= 1) {
        int t = (tid < VV && tid >= off) ? h[tid - off] : 0;
        __syncthreads();
        if (tid < VV) h[tid] += t;
        __syncthreads();
    }
    if (tid < VV) {
        int pre = h[tid] - own;
        starts_s[tid] = pre;
        offs[tid]     = pre;
    }
    __syncthreads();

    // placement from registers
    #pragma unroll
    for (int w = 0; w < NR2; ++w) {
        int k = tid + w * 512;
        if (k < cs) {
            uint2 v = regs[w];
            int p = atomicAdd(&offs[v.x >> 17], 1);
            if (p < CAP2) srec[p] = v;
        }
    }
    __syncthreads();

    // accumulate: 4 lanes per node, registers only
    int local = tid >> 2;
    int q     = tid & 3;
    int st = min(starts_s[local], CAP2);
    int en = min(h[local], CAP2);

    float acc[PP];
    #pragma unroll
    for (int p = 0; p < PP; ++p) acc[p] = 0.f;

    for (int m = st + q; m < en; m += 4) {
        uint2 v = srec[m];
        float c = __uint_as_float(v.y);
        const float4* xs = (const float4*)(xds + ((size_t)(v.x & 0x1FFFFu) << 4));
        float4 v0 = xs[0], v1 = xs[1], v2 = xs[2];
        acc[0] += c * v0.x;  acc[1] += c * v0.y;  acc[2]  += c * v0.z;  acc[3]  += c * v0.w;
        acc[4] += c * v1.x;  acc[5] += c * v1.y;  acc[6]  += c * v1.z;  acc[7]  += c * v1.w;
        acc[8] += c * v2.x;  acc[9] += c * v2.y;  acc[10] += c * v2.z;  acc[11] += c * v2.w;
    }

    // width-4 butterfly: all 4 lanes hold full sums
    #pragma unroll
    for (int p = 0; p < PP; ++p) {
        acc[p] += __shfl_xor(acc[p], 1, 4);
        acc[p] += __shfl_xor(acc[p], 2, 4);
    }

    // partial write: lane q writes floats 3q..3q+2 -> 48B contiguous per node
    float* ap = pagg + ((size_t)(seg * BB + b) * VV + local) * PP;
    ap[3 * q + 0] = acc[3 * q + 0];
    ap[3 * q + 1] = acc[3 * q + 1];
    ap[3 * q + 2] = acc[3 * q + 2];

    // last-finisher epilogue (deterministic: fixed combine order a0+a1+a2+a3)
    __threadfence();
    if (tid == 0) is_last = (atomicAdd(&cnt[b], 1) == NSEG - 1) ? 1 : 0;
    __syncthreads();
    if (!is_last) return;
    __threadfence();

    int g = tid >> 5;
    int j = tid & 31;
    float azj = tabs[16 + j];
    float czj = tabs[16 + FF + j];
    float ahj = tabs[16 + 2 * FF + j];
    float chj = tabs[16 + 3 * FF + j];

    for (int nl = g; nl < VV; nl += 16) {
        int i = b * VV + nl;
        if (i >= NN) continue;            // uniform within the 32-lane group
        float dv = xds[((size_t)i << 4) + 12];
        const float* a0 = pagg + ((size_t)b * VV + nl) * PP;
        const float* a1 = a0 + (size_t)BB * VV * PP;
        const float* a2 = a1 + (size_t)BB * VV * PP;
        const float* a3 = a2 + (size_t)BB * VV * PP;

        float accum = 0.f;
        #pragma unroll
        for (int p = 0; p < PP; ++p) {
            float ai = (a0[p] + a1[p]) + (a2[p] + a3[p]);
            float sp = dv * (ai + xds[((size_t)i << 4) + p]);  // edge sum + self
            float pr = tabs[p];
            float uz = sp * azj + czj;
            float uh = sp * ahj + chj;
            float one_minus_z = 1.0f / (1.0f + __expf(uz));   // sigma(-uz)
            float e2h = __expf(2.0f * uh);
            float th  = 1.0f - 2.0f / (e2h + 1.0f);           // tanh(uh)
            accum += pr * one_minus_z * th;
        }
        float hv = fmaxf(accum, 0.f) * w_out[j];
        #pragma unroll
        for (int off = 16; off > 0; off >>= 1)
            hv += __shfl_xor(hv, off, 32);
        if (j == 0) out[i] = hv + b_out[0];
    }
}

// ---------------- fallback path (round-2 proven kernels) ----------------
__global__ void precompute_k(const float* __restrict__ att,
                             const float* __restrict__ wc_z, const float* __restrict__ bc_z,
                             const float* __restrict__ wc_h, const float* __restrict__ bc_h,
                             const float* __restrict__ wl_z, const float* __restrict__ bl_z,
                             const float* __restrict__ wl_h, const float* __restrict__ bl_h,
                             float* __restrict__ tabs) {
    int j = threadIdx.x;
    if (j < FF) {
        float az = 0.f, cz = 0.f, ah = 0.f, ch = 0.f;
        for (int f = 0; f < FF; ++f) {
            float wz = wl_z[f * FF + j];
            float wh = wl_h[f * FF + j];
            az += wc_z[f] * wz;
            cz += bc_z[f] * wz;
            ah += wc_h[f] * wh;
            ch += bc_h[f] * wh;
        }
        tabs[16 + j]          = az;
        tabs[16 + FF + j]     = cz + bl_z[j];
        tabs[16 + 2 * FF + j] = ah;
        tabs[16 + 3 * FF + j] = ch + bl_h[j];
    } else if (j == FF) {
        float a[PP];
        float m = -1e30f;
        for (int p = 0; p < PP; ++p) { a[p] = att[p]; m = fmaxf(m, a[p]); }
        float s = 0.f;
        for (int p = 0; p < PP; ++p) { a[p] = __expf(a[p] - m); s += a[p]; }
        for (int p = 0; p < PP; ++p) tabs[p] = a[p] / s;
    }
}

__global__ __launch_bounds__(256) void deg_k(const int* __restrict__ dst,
                                             const float* __restrict__ ew,
                                             float* __restrict__ deg) {
    int stride = gridDim.x * blockDim.x;
    for (int e = blockIdx.x * blockDim.x + threadIdx.x; e < EE; e += stride)
        atomicAdd(&deg[dst[e]], ew[e]);
}

__global__ __launch_bounds__(256) void dinv_self_k(const float* __restrict__ x,
                                                   float* __restrict__ deg,
                                                   float* __restrict__ agg) {
    int i = blockIdx.x * blockDim.x + threadIdx.x;
    if (i >= NN) return;
    float d  = deg[i] + 1.0f;
    float dv = rsqrtf(d);
    deg[i]   = dv;
    float dv2 = dv * dv;
    const float4* xr = (const float4*)(x + (size_t)i * PP);
    float4* ar = (float4*)(agg + (size_t)i * PP);
    #pragma unroll
    for (int q = 0; q < 3; ++q) {
        float4 v = xr[q];
        v.x *= dv2; v.y *= dv2; v.z *= dv2; v.w *= dv2;
        ar[q] = v;
    }
}

__global__ __launch_bounds__(256) void agg_k(const int* __restrict__ src,
                                             const int* __restrict__ dst,
                                             const float* __restrict__ ew,
                                             const float* __restrict__ x,
                                             const float* __restrict__ dinv,
                                             float* __restrict__ agg) {
    int stride = gridDim.x * blockDim.x;
    for (int e = blockIdx.x * blockDim.x + threadIdx.x; e < EE; e += stride) {
        int s = src[e];
        int d = dst[e];
        float nw = dinv[s] * ew[e] * dinv[d];
        const float4* xs = (const float4*)(x + (size_t)s * PP);
        float* ad = agg + (size_t)d * PP;
        float4 v0 = xs[0], v1 = xs[1], v2 = xs[2];
        atomicAdd(&ad[0],  nw * v0.x);
        atomicAdd(&ad[1],  nw * v0.y);
        atomicAdd(&ad[2],  nw * v0.z);
        atomicAdd(&ad[3],  nw * v0.w);
        atomicAdd(&ad[4],  nw * v1.x);
        atomicAdd(&ad[5],  nw * v1.y);
        atomicAdd(&ad[6],  nw * v1.z);
        atomicAdd(&ad[7],  nw * v1.w);
        atomicAdd(&ad[8],  nw * v2.x);
        atomicAdd(&ad[9],  nw * v2.y);
        atomicAdd(&ad[10], nw * v2.z);
        atomicAdd(&ad[11], nw * v2.w);
    }
}

__global__ __launch_bounds__(256) void node_k(const float* __restrict__ agg,
                                              const float* __restrict__ tabs,
                                              const float* __restrict__ w_out,
                                              const float* __restrict__ b_out,
                                              float* __restrict__ out) {
    int t = blockIdx.x * blockDim.x + threadIdx.x;
    int i = t >> 5;
    int j = t & 31;
    if (i >= NN) return;
    float azj = tabs[16 + j];
    float czj = tabs[16 + FF + j];
    float ahj = tabs[16 + 2 * FF + j];
    float chj = tabs[16 + 3 * FF + j];
    float acc = 0.f;
    #pragma unroll
    for (int p = 0; p < PP; ++p) {
        float s  = agg[i * PP + p];
        float pr = tabs[p];
        float uz = s * azj + czj;
        float uh = s * ahj + chj;
        float one_minus_z = 1.0f / (1.0f + __expf(uz));
        float e2h = __expf(2.0f * uh);
        float th  = 1.0f - 2.0f / (e2h + 1.0f);
        acc += pr * one_minus_z * th;
    }
    float h = fmaxf(acc, 0.f) * w_out[j];
    #pragma unroll
    for (int off = 16; off > 0; off >>= 1)
        h += __shfl_xor(h, off, 32);
    if (j == 0) out[i] = h + b_out[0];
}

extern "C" void kernel_launch(void* const* d_in, const int* in_sizes, int n_in,
                              void* d_out, int out_size, void* d_ws, size_t ws_size,
                              hipStream_t stream) {
    const float* x    = (const float*)d_in[0];
    const int*   ei   = (const int*)d_in[1];
    const float* ew   = (const float*)d_in[2];
    const float* att  = (const float*)d_in[3];
    const float* wc_z = (const float*)d_in[4];
    const float* bc_z = (const float*)d_in[5];
    const float* wc_h = (const float*)d_in[8];
    const float* bc_h = (const float*)d_in[9];
    const float* wl_z = (const float*)d_in[10];
    const float* bl_z = (const float*)d_in[11];
    const float* wl_h = (const float*)d_in[14];
    const float* bl_h = (const float*)d_in[15];
    const float* wout = (const float*)d_in[16];
    const float* bout = (const float*)d_in[17];
    float* out = (float*)d_out;

    const int* src = ei;
    const int* dst = ei + EE;

    size_t recs_sz = (size_t)(BB + 2) * CAPB * sizeof(uint2);          // 55.4 MB (+guard)
    size_t tbl_sz  = (((size_t)BB * K1B * 2) + 63) & ~63ull;           // 1.25 MB
    size_t p32_sz  = (size_t)BB * K1B * sizeof(unsigned int);          // 2.50 MB
    size_t tot_sz  = ((size_t)BB * 4 + 63) & ~63ull;                   // 3.2 KB
    size_t xds_sz  = (size_t)NN * XST * sizeof(float);                 // 6.4 MB
    size_t pagg_sz = (size_t)NSEG * BB * VV * PP * sizeof(float);      // 19.2 MB
    size_t cnt_sz  = ((size_t)BB * 4 + 63) & ~63ull;
    size_t need    = recs_sz + tbl_sz + p32_sz + tot_sz + xds_sz + pagg_sz + cnt_sz + 4096;

    if (ws_size >= need) {
        char* base = (char*)d_ws;
        uint2*          recs2 = (uint2*)base;            base += recs_sz;
        unsigned short* T16   = (unsigned short*)base;   base += tbl_sz;
        unsigned int*   P32   = (unsigned int*)base;     base += p32_sz;
        unsigned int*   tot   = (unsigned int*)base;     base += tot_sz;
        float*          xds   = (float*)base;            base += xds_sz;
        float*          pagg  = (float*)base;            base += pagg_sz;
        int*            cnt   = (int*)base;              base += cnt_sz;
        float*          tabs  = (float*)base;

        hipMemsetAsync(cnt, 0, (size_t)BB * sizeof(int), stream);
        hist_k<<<K1B, 512, 0, stream>>>(dst, T16);
        scan_k<<<BB + 1, 512, 0, stream>>>(T16, P32, tot,
                                           att, wc_z, bc_z, wc_h, bc_h,
                                           wl_z, bl_z, wl_h, bl_h, tabs);
        sortwrite_k<<<K1B, 512, 0, stream>>>(src, dst, ew, T16, P32, recs2);
        degxds_k<<<BB, 512, 0, stream>>>(recs2, tot, x, xds);
        sortagg_k<<<BB * NSEG, 512, 0, stream>>>(recs2, tot, xds, pagg, cnt,
                                                 tabs, wout, bout, out);
    } else {
        float* deg  = (float*)d_ws;
        float* agg  = deg + NN;
        float* tabs = agg + (size_t)NN * PP;

        hipMemsetAsync(deg, 0, NN * sizeof(float), stream);
        precompute_k<<<1, 64, 0, stream>>>(att, wc_z, bc_z, wc_h, bc_h, wl_z, bl_z, wl_h, bl_h, tabs);
        deg_k<<<4096, 256, 0, stream>>>(dst, ew, deg);
        dinv_self_k<<<(NN + 255) / 256, 256, 0, stream>>>(x, deg, agg);
        agg_k<<<8192, 256, 0, stream>>>(src, dst, ew, x, deg, agg);
        node_k<<<NN * 32 / 256, 256, 0, stream>>>(agg, tabs, wout, bout, out);
    }
}

// Round 13
// 378.885 us; speedup vs baseline: 4.3749x; 4.3749x over previous
//
#include <hip/hip_runtime.h>

#define NN 100000
#define EE 6400000
#define PP 12
#define FF 32

// bucket = 128 consecutive node ids; recs2 is globally bucket-contiguous
#define VV    128           // nodes per bucket
#define BB    782           // ceil(NN/VV)
#define CAPB  8832          // per-bucket region capacity: mean 8192 + 7 sigma
#define K1B   800           // chunks
#define CHK   8000          // edges per chunk (K1B*CHK == EE)
#define NBIN  784           // hist bins padded (782 used)
#define XST   16            // xds row stride (floats): 64B -> one cache line per node
#define NSEG  4             // sortagg segments per bucket (contiguous quarters)
#define CAP2  2432          // per-segment LDS capacity >= ceil(CAPB/4)=2208
#define NR2   5             // records per thread (ceil(CAP2/512))
#define FPS   4294967296.0f // fixed-point scale 2^32
#define FPSI  (1.0f / 4294967296.0f)

// ---------------- K1a: per-chunk bucket histogram -> T16 counts ----------------
// T16[b*K1B + blk] = count of bucket-b records in chunk blk
__global__ __launch_bounds__(512) void hist_k(const int* __restrict__ dst,
                                              unsigned short* __restrict__ T16) {
    __shared__ int hist[NBIN];
    int tid = threadIdx.x;
    int blk = blockIdx.x;
    int beg = blk * CHK;

    for (int b = tid; b < NBIN; b += 512) hist[b] = 0;
    __syncthreads();

    for (int e = tid; e < CHK; e += 512)
        atomicAdd(&hist[dst[beg + e] >> 7], 1);
    __syncthreads();

    for (int b = tid; b < BB; b += 512)
        T16[(size_t)b * K1B + blk] = (unsigned short)hist[b];
}

// ---------------- K1b: per-bucket row scan -> P32 (excl prefix), tot; + precompute --
// block b<BB: P32[b][k] = sum of T16[b][0..k); tot[b] = row total
// block BB: GRU table precompute (tabs: [0..11] probs, [16..143] az/cz/ah/ch)
__global__ __launch_bounds__(512) void scan_k(const unsigned short* __restrict__ T16,
                                              unsigned int* __restrict__ P32,
                                              unsigned int* __restrict__ tot,
                                              const float* __restrict__ att,
                                              const float* __restrict__ wc_z, const float* __restrict__ bc_z,
                                              const float* __restrict__ wc_h, const float* __restrict__ bc_h,
                                              const float* __restrict__ wl_z, const float* __restrict__ bl_z,
                                              const float* __restrict__ wl_h, const float* __restrict__ bl_h,
                                              float* __restrict__ tabs) {
    int b = blockIdx.x;
    int tid = threadIdx.x;

    if (b == BB) {                      // fused precompute (one block)
        int j = tid;
        if (j < FF) {
            float az = 0.f, cz = 0.f, ah = 0.f, ch = 0.f;
            for (int f = 0; f < FF; ++f) {
                float wz = wl_z[f * FF + j];
                float wh = wl_h[f * FF + j];
                az += wc_z[f] * wz;
                cz += bc_z[f] * wz;
                ah += wc_h[f] * wh;
                ch += bc_h[f] * wh;
            }
            tabs[16 + j]          = az;
            tabs[16 + FF + j]     = cz + bl_z[j];
            tabs[16 + 2 * FF + j] = ah;
            tabs[16 + 3 * FF + j] = ch + bl_h[j];
        } else if (j == FF) {
            float a[PP];
            float m = -1e30f;
            for (int p = 0; p < PP; ++p) { a[p] = att[p]; m = fmaxf(m, a[p]); }
            float s = 0.f;
            for (int p = 0; p < PP; ++p) { a[p] = __expf(a[p] - m); s += a[p]; }
            for (int p = 0; p < PP; ++p) tabs[p] = a[p] / s;
        }
        return;
    }

    __shared__ int s[K1B];
    int i2 = tid + 512;
    s[tid] = T16[(size_t)b * K1B + tid];
    if (i2 < K1B) s[i2] = T16[(size_t)b * K1B + i2];
    __syncthreads();

    int own0 = s[tid];
    int own1 = (i2 < K1B) ? s[i2] : 0;
    for (int off = 1; off < K1B; off <<= 1) {   // off: 1..512
        int a0 = (tid >= off) ? s[tid - off] : 0;
        int a1 = (i2 < K1B) ? s[i2 - off] : 0;  // i2 >= 512 >= off always
        __syncthreads();
        s[tid] += a0;
        if (i2 < K1B) s[i2] += a1;
        __syncthreads();
    }
    P32[(size_t)b * K1B + tid] = (unsigned)(s[tid] - own0);
    if (i2 < K1B) P32[(size_t)b * K1B + i2] = (unsigned)(s[i2] - own1);
    if (tid == 0) tot[b] = (unsigned)s[K1B - 1];
}

// ---------------- K1c: chunk-sort in LDS, scatter runs to global bucket regions -----
// record: (local<<17)|src, bits(w); target recs2[b*CAPB + P32[b][blk] + rank]
__global__ __launch_bounds__(512) void sortwrite_k(const int* __restrict__ src,
                                                   const int* __restrict__ dst,
                                                   const float* __restrict__ ew,
                                                   const unsigned short* __restrict__ T16,
                                                   const unsigned int* __restrict__ P32,
                                                   uint2* __restrict__ recs2) {
    __shared__ unsigned int perm[CHK];      // 32000 B: (bucket<<20)|(local<<13)|e
    __shared__ int cnt_s[NBIN];             // counts -> inclusive scan
    __shared__ int offs[NBIN];              // claim counters (start at lstart)
    __shared__ unsigned short lstart[NBIN]; // chunk-local run starts
    __shared__ unsigned int gbase[NBIN];    // global run bases
    int tid = threadIdx.x;
    int blk = blockIdx.x;
    int beg = blk * CHK;

    for (int b = tid; b < NBIN; b += 512) {
        int c = (b < BB) ? (int)T16[(size_t)b * K1B + blk] : 0;
        cnt_s[b] = c;
        gbase[b] = (b < BB) ? (unsigned)(b * CAPB) + P32[(size_t)b * K1B + blk] : 0u;
    }
    __syncthreads();

    // inclusive Hillis-Steele scan over cnt_s[NBIN], 2 slots/thread
    int i2   = 512 + tid;
    int own0 = cnt_s[tid];
    int own1 = (i2 < NBIN) ? cnt_s[i2] : 0;
    for (int off = 1; off < NBIN; off <<= 1) {
        int a0 = (tid >= off) ? cnt_s[tid - off] : 0;
        int a1 = (i2 < NBIN) ? cnt_s[i2 - off] : 0;   // i2 >= 512 >= off always
        __syncthreads();
        cnt_s[tid] += a0;
        if (i2 < NBIN) cnt_s[i2] += a1;
        __syncthreads();
    }
    offs[tid]   = cnt_s[tid] - own0;
    lstart[tid] = (unsigned short)(cnt_s[tid] - own0);
    if (i2 < NBIN) {
        offs[i2]   = cnt_s[i2] - own1;
        lstart[i2] = (unsigned short)(cnt_s[i2] - own1);
    }
    __syncthreads();

    // placement: LDS claim atomic + 4B perm store (dst re-read is L1/L2-hot)
    for (int e = tid; e < CHK; e += 512) {
        int d = dst[beg + e];
        int b = d >> 7;
        int p = atomicAdd(&offs[b], 1);
        perm[p] = ((unsigned)b << 20) | ((unsigned)(d & (VV - 1)) << 13) | (unsigned)e;
    }
    __syncthreads();

    // write-out: runs land contiguous in their bucket region (82B avg granules)
    for (int k = tid; k < CHK; k += 512) {
        unsigned pe = perm[k];
        int b = (int)(pe >> 20);
        int e = (int)(pe & 0x1FFFu);
        unsigned g = gbase[b] + (unsigned)(k - (int)lstart[b]);
        if (g < (unsigned)((b + 1) * CAPB)) {
            uint2 r;
            r.x = (((pe >> 13) & 0x7Fu) << 17) | (unsigned)src[beg + e];
            r.y = __float_as_uint(ew[beg + e]);
            recs2[g] = r;
        }
    }
}

// ---------------- K2: per-bucket degree (coalesced stream + ds_add_u64) + xds -------
__global__ __launch_bounds__(512) void degxds_k(const uint2* __restrict__ recs2,
                                                const unsigned int* __restrict__ tot,
                                                const float* __restrict__ x,
                                                float* __restrict__ xds) {
    __shared__ unsigned long long wsum[VV];
    int b = blockIdx.x;
    int tid = threadIdx.x;
    if (tid < VV) wsum[tid] = 0ull;
    __syncthreads();

    int n = min((int)tot[b], CAPB);
    const uint2* r = recs2 + (size_t)b * CAPB;
    for (int k = tid; k < n; k += 512) {
        uint2 v = r[k];
        atomicAdd(&wsum[v.x >> 17],
                  (unsigned long long)(long long)(__uint_as_float(v.y) * FPS));
    }
    __syncthreads();

    int node = b * VV + tid;
    if (tid < VV && node < NN) {
        float wf = (float)wsum[tid] * FPSI;
        float dv = rsqrtf(wf + 1.0f);
        const float4* xr = (const float4*)(x + (size_t)node * PP);
        float4* xo = (float4*)(xds + ((size_t)node << 4));
        #pragma unroll
        for (int q = 0; q < 3; ++q) {
            float4 v = xr[q];
            v.x *= dv; v.y *= dv; v.z *= dv; v.w *= dv;
            xo[q] = v;
        }
        xds[((size_t)node << 4) + 12] = dv;
    }
}

// ---------------- K3: sortagg on contiguous quarters -> partial pagg ----------------
__global__ __launch_bounds__(512) void sortagg_k(const uint2* __restrict__ recs2,
                                                 const unsigned int* __restrict__ tot,
                                                 const float* __restrict__ xds,
                                                 float* __restrict__ pagg) {
    __shared__ uint2 srec[CAP2];                    // 19456 B
    __shared__ int   h[VV], starts_s[VV], offs[VV]; // 1536 B (h keeps inclusive ends)
    int b   = blockIdx.x >> 2;
    int seg = blockIdx.x & 3;
    int tid = threadIdx.x;

    int n  = min((int)tot[b], CAPB);
    int lo = (n * seg) >> 2;
    int hi = (n * (seg + 1)) >> 2;
    int cs = hi - lo;                               // <= ceil(CAPB/4) = 2208 <= CAP2
    const uint2* base = recs2 + (size_t)b * CAPB + lo;

    if (tid < VV) h[tid] = 0;
    __syncthreads();

    // dense coalesced load into REGISTERS + node histogram
    uint2 regs[NR2];
    #pragma unroll
    for (int w = 0; w < NR2; ++w) {
        int k = tid + w * 512;
        if (k < cs) {
            uint2 v = base[k];
            regs[w] = v;
            atomicAdd(&h[v.x >> 17], 1);
        }
    }
    __syncthreads();

    // Hillis-Steele inclusive scan over h[VV]; h stays = inclusive end
    int own = (tid < VV) ? h[tid] : 0;
    #pragma unroll
    for (int off = 1; off < VV; off <<= 1) {
        int t = (tid < VV && tid >= off) ? h[tid - off] : 0;
        __syncthreads();
        if (tid < VV) h[tid] += t;
        __syncthreads();
    }
    if (tid < VV) {
        int pre = h[tid] - own;
        starts_s[tid] = pre;
        offs[tid]     = pre;
    }
    __syncthreads();

    // placement from registers
    #pragma unroll
    for (int w = 0; w < NR2; ++w) {
        int k = tid + w * 512;
        if (k < cs) {
            uint2 v = regs[w];
            int p = atomicAdd(&offs[v.x >> 17], 1);
            if (p < CAP2) srec[p] = v;
        }
    }
    __syncthreads();

    // accumulate: 4 lanes per node, registers only
    int local = tid >> 2;
    int q     = tid & 3;
    int st = min(starts_s[local], CAP2);
    int en = min(h[local], CAP2);

    float acc[PP];
    #pragma unroll
    for (int p = 0; p < PP; ++p) acc[p] = 0.f;

    for (int m = st + q; m < en; m += 4) {
        uint2 v = srec[m];
        float c = __uint_as_float(v.y);
        const float4* xs = (const float4*)(xds + ((size_t)(v.x & 0x1FFFFu) << 4));
        float4 v0 = xs[0], v1 = xs[1], v2 = xs[2];
        acc[0] += c * v0.x;  acc[1] += c * v0.y;  acc[2]  += c * v0.z;  acc[3]  += c * v0.w;
        acc[4] += c * v1.x;  acc[5] += c * v1.y;  acc[6]  += c * v1.z;  acc[7]  += c * v1.w;
        acc[8] += c * v2.x;  acc[9] += c * v2.y;  acc[10] += c * v2.z;  acc[11] += c * v2.w;
    }

    // width-4 butterfly: all 4 lanes hold full sums
    #pragma unroll
    for (int p = 0; p < PP; ++p) {
        acc[p] += __shfl_xor(acc[p], 1, 4);
        acc[p] += __shfl_xor(acc[p], 2, 4);
    }

    // partial write: lane q writes floats 3q..3q+2 -> 48B contiguous per node
    float* ap = pagg + ((size_t)(seg * BB + b) * VV + local) * PP;
    ap[3 * q + 0] = acc[3 * q + 0];
    ap[3 * q + 1] = acc[3 * q + 1];
    ap[3 * q + 2] = acc[3 * q + 2];
}

// ---------------- K4: combine 4 partials + fused GRU/attention/output ---------------
__global__ __launch_bounds__(512) void epi_k(const float* __restrict__ pagg,
                                             const float* __restrict__ xds,
                                             const float* __restrict__ tabs,
                                             const float* __restrict__ w_out,
                                             const float* __restrict__ b_out,
                                             float* __restrict__ out) {
    int b = blockIdx.x;
    int tid = threadIdx.x;
    int g = tid >> 5;
    int j = tid & 31;
    float azj = tabs[16 + j];
    float czj = tabs[16 + FF + j];
    float ahj = tabs[16 + 2 * FF + j];
    float chj = tabs[16 + 3 * FF + j];

    for (int nl = g; nl < VV; nl += 16) {
        int i = b * VV + nl;
        if (i >= NN) continue;            // uniform within the 32-lane group
        float dv = xds[((size_t)i << 4) + 12];
        const float* a0 = pagg + ((size_t)b * VV + nl) * PP;
        const float* a1 = a0 + (size_t)BB * VV * PP;
        const float* a2 = a1 + (size_t)BB * VV * PP;
        const float* a3 = a2 + (size_t)BB * VV * PP;

        float accum = 0.f;
        #pragma unroll
        for (int p = 0; p < PP; ++p) {
            float ai = (a0[p] + a1[p]) + (a2[p] + a3[p]);
            float sp = dv * (ai + xds[((size_t)i << 4) + p]);  // edge sum + self
            float pr = tabs[p];
            float uz = sp * azj + czj;
            float uh = sp * ahj + chj;
            float one_minus_z = 1.0f / (1.0f + __expf(uz));   // sigma(-uz)
            float e2h = __expf(2.0f * uh);
            float th  = 1.0f - 2.0f / (e2h + 1.0f);           // tanh(uh)
            accum += pr * one_minus_z * th;
        }
        float hv = fmaxf(accum, 0.f) * w_out[j];
        #pragma unroll
        for (int off = 16; off > 0; off >>= 1)
            hv += __shfl_xor(hv, off, 32);
        if (j == 0) out[i] = hv + b_out[0];
    }
}

// ---------------- fallback path (round-2 proven kernels) ----------------
__global__ void precompute_k(const float* __restrict__ att,
                             const float* __restrict__ wc_z, const float* __restrict__ bc_z,
                             const float* __restrict__ wc_h, const float* __restrict__ bc_h,
                             const float* __restrict__ wl_z, const float* __restrict__ bl_z,
                             const float* __restrict__ wl_h, const float* __restrict__ bl_h,
                             float* __restrict__ tabs) {
    int j = threadIdx.x;
    if (j < FF) {
        float az = 0.f, cz = 0.f, ah = 0.f, ch = 0.f;
        for (int f = 0; f < FF; ++f) {
            float wz = wl_z[f * FF + j];
            float wh = wl_h[f * FF + j];
            az += wc_z[f] * wz;
            cz += bc_z[f] * wz;
            ah += wc_h[f] * wh;
            ch += bc_h[f] * wh;
        }
        tabs[16 + j]          = az;
        tabs[16 + FF + j]     = cz + bl_z[j];
        tabs[16 + 2 * FF + j] = ah;
        tabs[16 + 3 * FF + j] = ch + bl_h[j];
    } else if (j == FF) {
        float a[PP];
        float m = -1e30f;
        for (int p = 0; p < PP; ++p) { a[p] = att[p]; m = fmaxf(m, a[p]); }
        float s = 0.f;
        for (int p = 0; p < PP; ++p) { a[p] = __expf(a[p] - m); s += a[p]; }
        for (int p = 0; p < PP; ++p) tabs[p] = a[p] / s;
    }
}

__global__ __launch_bounds__(256) void deg_k(const int* __restrict__ dst,
                                             const float* __restrict__ ew,
                                             float* __restrict__ deg) {
    int stride = gridDim.x * blockDim.x;
    for (int e = blockIdx.x * blockDim.x + threadIdx.x; e < EE; e += stride)
        atomicAdd(&deg[dst[e]], ew[e]);
}

__global__ __launch_bounds__(256) void dinv_self_k(const float* __restrict__ x,
                                                   float* __restrict__ deg,
                                                   float* __restrict__ agg) {
    int i = blockIdx.x * blockDim.x + threadIdx.x;
    if (i >= NN) return;
    float d  = deg[i] + 1.0f;
    float dv = rsqrtf(d);
    deg[i]   = dv;
    float dv2 = dv * dv;
    const float4* xr = (const float4*)(x + (size_t)i * PP);
    float4* ar = (float4*)(agg + (size_t)i * PP);
    #pragma unroll
    for (int q = 0; q < 3; ++q) {
        float4 v = xr[q];
        v.x *= dv2; v.y *= dv2; v.z *= dv2; v.w *= dv2;
        ar[q] = v;
    }
}

__global__ __launch_bounds__(256) void agg_k(const int* __restrict__ src,
                                             const int* __restrict__ dst,
                                             const float* __restrict__ ew,
                                             const float* __restrict__ x,
                                             const float* __restrict__ dinv,
                                             float* __restrict__ agg) {
    int stride = gridDim.x * blockDim.x;
    for (int e = blockIdx.x * blockDim.x + threadIdx.x; e < EE; e += stride) {
        int s = src[e];
        int d = dst[e];
        float nw = dinv[s] * ew[e] * dinv[d];
        const float4* xs = (const float4*)(x + (size_t)s * PP);
        float* ad = agg + (size_t)d * PP;
        float4 v0 = xs[0], v1 = xs[1], v2 = xs[2];
        atomicAdd(&ad[0],  nw * v0.x);
        atomicAdd(&ad[1],  nw * v0.y);
        atomicAdd(&ad[2],  nw * v0.z);
        atomicAdd(&ad[3],  nw * v0.w);
        atomicAdd(&ad[4],  nw * v1.x);
        atomicAdd(&ad[5],  nw * v1.y);
        atomicAdd(&ad[6],  nw * v1.z);
        atomicAdd(&ad[7],  nw * v1.w);
        atomicAdd(&ad[8],  nw * v2.x);
        atomicAdd(&ad[9],  nw * v2.y);
        atomicAdd(&ad[10], nw * v2.z);
        atomicAdd(&ad[11], nw * v2.w);
    }
}

__global__ __launch_bounds__(256) void node_k(const float* __restrict__ agg,
                                              const float* __restrict__ tabs,
                                              const float* __restrict__ w_out,
                                              const float* __restrict__ b_out,
                                              float* __restrict__ out) {
    int t = blockIdx.x * blockDim.x + threadIdx.x;
    int i = t >> 5;
    int j = t & 31;
    if (i >= NN) return;
    float azj = tabs[16 + j];
    float czj = tabs[16 + FF + j];
    float ahj = tabs[16 + 2 * FF + j];
    float chj = tabs[16 + 3 * FF + j];
    float acc = 0.f;
    #pragma unroll
    for (int p = 0; p < PP; ++p) {
        float s  = agg[i * PP + p];
        float pr = tabs[p];
        float uz = s * azj + czj;
        float uh = s * ahj + chj;
        float one_minus_z = 1.0f / (1.0f + __expf(uz));
        float e2h = __expf(2.0f * uh);
        float th  = 1.0f - 2.0f / (e2h + 1.0f);
        acc += pr * one_minus_z * th;
    }
    float h = fmaxf(acc, 0.f) * w_out[j];
    #pragma unroll
    for (int off = 16; off > 0; off >>= 1)
        h += __shfl_xor(h, off, 32);
    if (j == 0) out[i] = h + b_out[0];
}

extern "C" void kernel_launch(void* const* d_in, const int* in_sizes, int n_in,
                              void* d_out, int out_size, void* d_ws, size_t ws_size,
                              hipStream_t stream) {
    const float* x    = (const float*)d_in[0];
    const int*   ei   = (const int*)d_in[1];
    const float* ew   = (const float*)d_in[2];
    const float* att  = (const float*)d_in[3];
    const float* wc_z = (const float*)d_in[4];
    const float* bc_z = (const float*)d_in[5];
    const float* wc_h = (const float*)d_in[8];
    const float* bc_h = (const float*)d_in[9];
    const float* wl_z = (const float*)d_in[10];
    const float* bl_z = (const float*)d_in[11];
    const float* wl_h = (const float*)d_in[14];
    const float* bl_h = (const float*)d_in[15];
    const float* wout = (const float*)d_in[16];
    const float* bout = (const float*)d_in[17];
    float* out = (float*)d_out;

    const int* src = ei;
    const int* dst = ei + EE;

    size_t recs_sz = (size_t)(BB + 2) * CAPB * sizeof(uint2);          // 55.4 MB (+guard)
    size_t tbl_sz  = (((size_t)BB * K1B * 2) + 63) & ~63ull;           // 1.25 MB
    size_t p32_sz  = (size_t)BB * K1B * sizeof(unsigned int);          // 2.50 MB
    size_t tot_sz  = ((size_t)BB * 4 + 63) & ~63ull;                   // 3.2 KB
    size_t xds_sz  = (size_t)NN * XST * sizeof(float);                 // 6.4 MB
    size_t pagg_sz = (size_t)NSEG * BB * VV * PP * sizeof(float);      // 19.2 MB
    size_t need    = recs_sz + tbl_sz + p32_sz + tot_sz + xds_sz + pagg_sz + 4096;

    if (ws_size >= need) {
        char* base = (char*)d_ws;
        uint2*          recs2 = (uint2*)base;            base += recs_sz;
        unsigned short* T16   = (unsigned short*)base;   base += tbl_sz;
        unsigned int*   P32   = (unsigned int*)base;     base += p32_sz;
        unsigned int*   tot   = (unsigned int*)base;     base += tot_sz;
        float*          xds   = (float*)base;            base += xds_sz;
        float*          pagg  = (float*)base;            base += pagg_sz;
        float*          tabs  = (float*)base;

        hist_k<<<K1B, 512, 0, stream>>>(dst, T16);
        scan_k<<<BB + 1, 512, 0, stream>>>(T16, P32, tot,
                                           att, wc_z, bc_z, wc_h, bc_h,
                                           wl_z, bl_z, wl_h, bl_h, tabs);
        sortwrite_k<<<K1B, 512, 0, stream>>>(src, dst, ew, T16, P32, recs2);
        degxds_k<<<BB, 512, 0, stream>>>(recs2, tot, x, xds);
        sortagg_k<<<BB * NSEG, 512, 0, stream>>>(recs2, tot, xds, pagg);
        epi_k<<<BB, 512, 0, stream>>>(pagg, xds, tabs, wout, bout, out);
    } else {
        float* deg  = (float*)d_ws;
        float* agg  = deg + NN;
        float* tabs = agg + (size_t)NN * PP;

        hipMemsetAsync(deg, 0, NN * sizeof(float), stream);
        precompute_k<<<1, 64, 0, stream>>>(att, wc_z, bc_z, wc_h, bc_h, wl_z, bl_z, wl_h, bl_h, tabs);
        deg_k<<<4096, 256, 0, stream>>>(dst, ew, deg);
        dinv_self_k<<<(NN + 255) / 256, 256, 0, stream>>>(x, deg, agg);
        agg_k<<<8192, 256, 0, stream>>>(src, dst, ew, x, deg, agg);
        node_k<<<NN * 32 / 256, 256, 0, stream>>>(agg, tabs, wout, bout, out);
    }
}